// Round 11
// baseline (100.796 us; speedup 1.0000x reference)
//
#include <hip/hip_runtime.h>
#include <math.h>

// QRNN: B=8, T=4096, C=256, UNITS=256, WINDOW=2
// gates = concat(x[t-1],x[t]) @ K[512,768] + bias ; z=tanh f=sig o=sig
// c_t = f*c_{t-1} + (1-f)*z_t ; h = sig(o)*c
// R11: block tile 128x256 (one gate per blockIdx.y), 4 waves, wave tile
// 64x128 (acc[4][8]): 12 frag reads / 32 MFMA per K-step, A-staging amortized
// over 2x columns. R4-proven loop (2-buf, stage(k+1); compute(k); syncthreads).

#define Bq 8
#define Tq 4096
#define NCq 64
#define Lq 64

typedef __attribute__((ext_vector_type(8))) _Float16 f16x8;
typedef __attribute__((ext_vector_type(4))) float f32x4;

__device__ __forceinline__ float sigmoidf_(float x) {
    return 1.f / (1.f + __expf(-x));
}
__device__ __forceinline__ float tanh_fast(float x) {
    return 1.f - 2.f / (__expf(2.f * x) + 1.f);
}
__device__ __forceinline__ unsigned short f16b(float a) {
    _Float16 h = (_Float16)a;
    return *(unsigned short*)&h;
}
__device__ __forceinline__ void gload16(const void* g, void* l) {
    __builtin_amdgcn_global_load_lds(
        (const __attribute__((address_space(1))) void*)g,
        (__attribute__((address_space(3))) void*)l, 16, 0, 0);
}

// ---------- prep: x -> padded fp16 xp[b][t+1][c]  AND  kw -> transposed bth
__global__ __launch_bounds__(256) void split_xk(
    const float* __restrict__ x, const float* __restrict__ kw,
    _Float16* __restrict__ xh, _Float16* __restrict__ bh)
{
    const int NX = Bq * 4097 * 64;
    int idx = blockIdx.x * 256 + threadIdx.x;
    if (idx < NX) {
        int b  = idx / (4097 * 64);
        int r  = idx % (4097 * 64);
        int tp = r / 64, c4 = (r % 64) << 2;
        size_t o = ((size_t)(b * 4097 + tp) << 8) + c4;
        _Float16 h4[4] = {(_Float16)0.f, (_Float16)0.f, (_Float16)0.f, (_Float16)0.f};
        if (tp > 0) {
            const float4 v = *(const float4*)&x[((size_t)(b * 4096 + tp - 1) << 8) + c4];
            h4[0] = (_Float16)v.x; h4[1] = (_Float16)v.y;
            h4[2] = (_Float16)v.z; h4[3] = (_Float16)v.w;
        }
        *(ushort4*)&xh[o] = *(ushort4*)h4;
    } else {
        int j = idx - NX;
        if (j < 768 * 512) {
            int n = j >> 9, k = j & 511;
            bh[((size_t)n << 9) + k] = (_Float16)kw[(size_t)k * 768 + n];
        }
    }
}

// ---------- main GEMM: 128x256 tile, BK=32, 4 waves (2x2), 16x16x32 f16 MFMA
__global__ __launch_bounds__(256, 2) void conv_gemm(
    const _Float16* __restrict__ xh, const _Float16* __restrict__ bth,
    const float* __restrict__ bias,
    _Float16* __restrict__ Z, _Float16* __restrict__ G, _Float16* __restrict__ SO)
{
    __shared__ __align__(16) char smem[65536];   // loop: 2 x (A 8KB + B 16KB); epi 64KB
    const int tid = threadIdx.x;
    const int l = tid & 63, w = tid >> 6;
    const int wr = w >> 1, wc = w & 1;           // wave tile 64 t x 128 n
    const int lg = l >> 4, l15 = l & 15;
    const int bm = blockIdx.x;            // 0..255  (M tiles, 128 rows each)
    const int by = blockIdx.y;            // 0..2 == gate
    const int b  = bm >> 5;
    const int t0 = (bm & 31) << 7;
    const int n0 = by << 8;

    f32x4 acc[4][8] = {};

    // staging: LDS linear dest; source k pre-swizzled: slot ^ ((row>>1)&3)
    const int rowT   = tid >> 2;
    const int slotSw = (tid & 3) ^ ((rowT >> 1) & 3);   // row+64 preserves (row>>1)&3
    size_t gaBase = ((size_t)(b * 4097 + t0 + rowT) << 8) + (slotSw << 3);
    size_t gbBase = ((size_t)(n0 + rowT) << 9) + (slotSw << 3);
    const int ldsW = w << 10;   // wave dest base within gload group (bytes)

    int offA[4], offB[8];
    #pragma unroll
    for (int i = 0; i < 4; ++i) {
        int ra = wr * 64 + i * 16 + l15;
        offA[i] = ((ra << 6) + (lg << 4)) ^ (((ra >> 1) & 3) << 4);
    }
    #pragma unroll
    for (int i = 0; i < 8; ++i) {
        int rb = wc * 128 + i * 16 + l15;
        offB[i] = ((rb << 6) + (lg << 4)) ^ (((rb >> 1) & 3) << 4);
    }

    auto stage = [&](int buf, int kk) {
        char* bA = smem + buf * 24576;
        char* bB = bA + 8192;
        size_t ga = gaBase + (size_t)kk * 32;   // rolls into next t-row for kk>=8
        size_t gb = gbBase + (size_t)kk * 32;
        #pragma unroll
        for (int g = 0; g < 2; ++g)             // A: 128 rows x 64B
            gload16(xh + ga + (size_t)g * 16384, bA + g * 4096 + ldsW);
        #pragma unroll
        for (int g = 0; g < 4; ++g)             // B: 256 rows x 64B
            gload16(bth + gb + (size_t)g * 32768, bB + g * 4096 + ldsW);
    };

    auto compute = [&](int buf) {
        const char* bA = smem + buf * 24576;
        const char* bB = bA + 8192;
        f16x8 fa[4], fb[8];
        #pragma unroll
        for (int i = 0; i < 4; ++i) fa[i] = *(const f16x8*)(bA + offA[i]);
        #pragma unroll
        for (int i = 0; i < 8; ++i) fb[i] = *(const f16x8*)(bB + offB[i]);
        __builtin_amdgcn_s_setprio(1);
        #pragma unroll
        for (int mi = 0; mi < 4; ++mi)
            #pragma unroll
            for (int ni = 0; ni < 8; ++ni)
                acc[mi][ni] = __builtin_amdgcn_mfma_f32_16x16x32_f16(
                    fa[mi], fb[ni], acc[mi][ni], 0, 0, 0);
        __builtin_amdgcn_s_setprio(0);
    };

    stage(0, 0);
    __syncthreads();
    int buf = 0;
    #pragma unroll
    for (int kk = 0; kk < 16; ++kk) {
        if (kk < 15) stage(buf ^ 1, kk + 1);   // prefetch before compute
        compute(buf);
        __syncthreads();                       // drains vmcnt (prefetch) + lgkm
        buf ^= 1;
    }

    // ---- epilogue: bias + activation -> LDS [128r][512B] transpose -> stores
    const int gsel = by;   // 0:z 1:f(store g=1-f) 2:o
    float bb[8];
    #pragma unroll
    for (int ni = 0; ni < 8; ++ni)
        bb[ni] = bias[n0 + wc * 128 + ni * 16 + l15];

    unsigned short* Hd = (unsigned short*)smem;   // 64KB 128x256 fp16 tile
    #pragma unroll
    for (int ni = 0; ni < 8; ++ni) {
        const int cl = wc * 128 + ni * 16 + l15;
        #pragma unroll
        for (int mi = 0; mi < 4; ++mi)
            #pragma unroll
            for (int r = 0; r < 4; ++r) {
                const int trl = wr * 64 + mi * 16 + lg * 4 + r;
                float g = acc[mi][ni][r] + bb[ni];
                float a = (gsel == 0) ? tanh_fast(g)
                        : (gsel == 1) ? sigmoidf_(-g)   // g = 1 - f
                                      : sigmoidf_(g);
                int byt = (trl << 9) + ((cl << 1) ^ (((trl >> 2) & 3) << 4));
                *(unsigned short*)((char*)Hd + byt) = f16b(a);
            }
    }
    __syncthreads();
    _Float16* Gg = (gsel == 0) ? Z : (gsel == 1) ? G : SO;
    const size_t gbase = ((size_t)(b * 4096 + t0)) << 8;  // halves
    #pragma unroll
    for (int i = 0; i < 16; ++i) {
        int off = (i * 256 + tid) << 4;        // bytes
        int row = off >> 9;
        int cby = off & 511;
        int src = (row << 9) + (cby ^ (((row >> 2) & 3) << 4));
        int4 v = *(const int4*)((const char*)Hd + src);
        *(int4*)&Gg[gbase + ((size_t)row << 8) + (cby >> 1)] = v;
    }
}

// ---------- scan kernels
__global__ __launch_bounds__(256) void chunk_reduce(
    const _Float16* __restrict__ Z, const _Float16* __restrict__ G,
    float* __restrict__ CA, float* __restrict__ CB)
{
    const int u = threadIdx.x;
    const int blk = blockIdx.x;
    const int b = blk >> 6, ck = blk & 63;
    size_t base = (((size_t)b << 12) + ck * Lq) * 256 + u;
    float A = 1.f, Bv = 0.f;
    #pragma unroll 8
    for (int s = 0; s < Lq; ++s) {
        size_t idx = base + (size_t)s * 256;
        float g = (float)G[idx];
        float z = (float)Z[idx];
        Bv = fmaf(1.f - g, Bv, g * z);
        A *= (1.f - g);
    }
    size_t cidx = ((size_t)b * NCq + ck) * 256 + u;
    CA[cidx] = A;
    CB[cidx] = Bv;
}

__global__ __launch_bounds__(256) void carry_scan(
    const float* __restrict__ CA, const float* __restrict__ CB,
    float* __restrict__ CIN)
{
    const int u = threadIdx.x;
    const int b = blockIdx.x;
    float c = 0.f;
    #pragma unroll 8
    for (int k = 0; k < NCq; ++k) {
        size_t idx = ((size_t)b * NCq + k) * 256 + u;
        CIN[idx] = c;
        c = fmaf(CA[idx], c, CB[idx]);
    }
}

__global__ __launch_bounds__(256) void apply_scan(
    const _Float16* __restrict__ Z, const _Float16* __restrict__ G,
    const _Float16* __restrict__ SO, const float* __restrict__ CIN,
    float* __restrict__ out)
{
    const int u = threadIdx.x;
    const int blk = blockIdx.x;
    const int b = blk >> 6, ck = blk & 63;
    float c = CIN[((size_t)b * NCq + ck) * 256 + u];
    size_t base = (((size_t)b << 12) + ck * Lq) * 256 + u;
    #pragma unroll 8
    for (int s = 0; s < Lq; ++s) {
        size_t idx = base + (size_t)s * 256;
        float g = (float)G[idx], z = (float)Z[idx];
        c = fmaf(1.f - g, c, g * z);
        out[idx] = (float)SO[idx] * c;
    }
}

extern "C" void kernel_launch(void* const* d_in, const int* in_sizes, int n_in,
                              void* d_out, int out_size, void* d_ws, size_t ws_size,
                              hipStream_t stream) {
    const float* x    = (const float*)d_in[0];
    const float* kw   = (const float*)d_in[1];
    const float* bias = (const float*)d_in[2];
    float* out = (float*)d_out;

    char* p = (char*)d_ws;
    _Float16* xh  = (_Float16*)p; p += (size_t)Bq * 4097 * 256 * 2;
    _Float16* bth = (_Float16*)p; p += (size_t)768 * 512 * 2;
    _Float16* Z   = (_Float16*)p; p += (size_t)Bq * Tq * 256 * 2;
    _Float16* G   = (_Float16*)p; p += (size_t)Bq * Tq * 256 * 2;
    _Float16* SO  = (_Float16*)p; p += (size_t)Bq * Tq * 256 * 2;
    float* CA  = (float*)p; p += (size_t)Bq * NCq * 256 * 4;
    float* CB  = (float*)p; p += (size_t)Bq * NCq * 256 * 4;
    float* CIN = (float*)p;

    const int NX = Bq * 4097 * 64;
    split_xk<<<(NX + 768 * 512 + 255) / 256, 256, 0, stream>>>(x, kw, xh, bth);
    dim3 g1(256, 3);
    conv_gemm<<<g1, 256, 0, stream>>>(xh, bth, bias, Z, G, SO);
    chunk_reduce<<<512, 256, 0, stream>>>(Z, G, CA, CB);
    carry_scan<<<Bq, 256, 0, stream>>>(CA, CB, CIN);
    apply_scan<<<512, 256, 0, stream>>>(Z, G, SO, CIN, out);
}

// Round 12
// 92.918 us; speedup vs baseline: 1.0848x; 1.0848x over previous
//
#include <hip/hip_runtime.h>
#include <math.h>

// QRNN: B=8, T=4096, C=256, UNITS=256, WINDOW=2
// gates = concat(x[t-1],x[t]) @ K[512,768] + bias ; z=tanh f=sig o=sig
// c_t = f*c_{t-1} + (1-f)*z_t ; h = sig(o)*c
// R12: SMALL tile 64x128 (wave tile 32x64, acc[2][4]) for ~5 blocks/CU
// occupancy (series shows conv time ~ 1/occupancy; every bigger-tile move
// regressed). LDS 24KB dbuf, R4-proven staging/swizzle/epilogue idioms.
// carry_scan fused into apply_scan (launch boundary = sync; CIN dropped).

#define Bq 8
#define Tq 4096
#define NCq 64
#define Lq 64

typedef __attribute__((ext_vector_type(8))) _Float16 f16x8;
typedef __attribute__((ext_vector_type(4))) float f32x4;

__device__ __forceinline__ float sigmoidf_(float x) {
    return 1.f / (1.f + __expf(-x));
}
__device__ __forceinline__ float tanh_fast(float x) {
    return 1.f - 2.f / (__expf(2.f * x) + 1.f);
}
__device__ __forceinline__ unsigned short f16b(float a) {
    _Float16 h = (_Float16)a;
    return *(unsigned short*)&h;
}
__device__ __forceinline__ void gload16(const void* g, void* l) {
    __builtin_amdgcn_global_load_lds(
        (const __attribute__((address_space(1))) void*)g,
        (__attribute__((address_space(3))) void*)l, 16, 0, 0);
}

// ---------- prep: x -> padded fp16 xp[b][t+1][c]  AND  kw -> transposed bth
__global__ __launch_bounds__(256) void split_xk(
    const float* __restrict__ x, const float* __restrict__ kw,
    _Float16* __restrict__ xh, _Float16* __restrict__ bh)
{
    const int NX = Bq * 4097 * 64;
    int idx = blockIdx.x * 256 + threadIdx.x;
    if (idx < NX) {
        int b  = idx / (4097 * 64);
        int r  = idx % (4097 * 64);
        int tp = r / 64, c4 = (r % 64) << 2;
        size_t o = ((size_t)(b * 4097 + tp) << 8) + c4;
        _Float16 h4[4] = {(_Float16)0.f, (_Float16)0.f, (_Float16)0.f, (_Float16)0.f};
        if (tp > 0) {
            const float4 v = *(const float4*)&x[((size_t)(b * 4096 + tp - 1) << 8) + c4];
            h4[0] = (_Float16)v.x; h4[1] = (_Float16)v.y;
            h4[2] = (_Float16)v.z; h4[3] = (_Float16)v.w;
        }
        *(ushort4*)&xh[o] = *(ushort4*)h4;
    } else {
        int j = idx - NX;
        if (j < 768 * 512) {
            int n = j >> 9, k = j & 511;
            bh[((size_t)n << 9) + k] = (_Float16)kw[(size_t)k * 768 + n];
        }
    }
}

// ---------- main GEMM: 64x128 tile, BK=32, 4 waves (2x2), 16x16x32 f16 MFMA
__global__ __launch_bounds__(256) void conv_gemm(
    const _Float16* __restrict__ xh, const _Float16* __restrict__ bth,
    const float* __restrict__ bias,
    _Float16* __restrict__ Z, _Float16* __restrict__ G, _Float16* __restrict__ SO)
{
    __shared__ __align__(16) char smem[24576];   // 2 bufs x (A 4KB + B 8KB); epi 16KB
    const int tid = threadIdx.x;
    const int l = tid & 63, w = tid >> 6;
    const int wr = w >> 1, wc = w & 1;           // wave tile 32 t x 64 n
    const int lg = l >> 4, l15 = l & 15;
    const int bm = blockIdx.x;            // 0..511  (M tiles, 64 rows each)
    const int by = blockIdx.y;            // 0..5
    const int b  = bm >> 6;
    const int t0 = (bm & 63) << 6;
    const int n0 = by << 7;               // within 768
    const int gsel = by >> 1;             // 0:z 1:f 2:o
    const int u0 = (by & 1) << 7;         // within 256

    f32x4 acc[2][4] = {};

    // staging: LDS linear dest; source k pre-swizzled: slot ^ ((row>>1)&3)
    const int rowT   = tid >> 2;          // 0..63
    const int slotSw = (tid & 3) ^ ((rowT >> 1) & 3);
    size_t gaBase = ((size_t)(b * 4097 + t0 + rowT) << 8) + (slotSw << 3);
    size_t gbBase = ((size_t)(n0 + rowT) << 9) + (slotSw << 3);
    const int ldsW = w << 10;             // wave dest base (bytes)

    int offA[2], offB[4];
    #pragma unroll
    for (int i = 0; i < 2; ++i) {
        int ra = wr * 32 + i * 16 + l15;
        offA[i] = ((ra << 6) + (lg << 4)) ^ (((ra >> 1) & 3) << 4);
    }
    #pragma unroll
    for (int i = 0; i < 4; ++i) {
        int rb = wc * 64 + i * 16 + l15;
        offB[i] = ((rb << 6) + (lg << 4)) ^ (((rb >> 1) & 3) << 4);
    }

    auto stage = [&](int buf, int kk) {
        char* bA = smem + buf * 12288;
        char* bB = bA + 4096;
        size_t ga = gaBase + (size_t)kk * 32;   // rolls into next t-row for kk>=8
        size_t gb = gbBase + (size_t)kk * 32;
        gload16(xh + ga, bA + ldsW);            // A: 64 rows x 64B
        #pragma unroll
        for (int g = 0; g < 2; ++g)             // B: 128 rows x 64B
            gload16(bth + gb + (size_t)g * 32768, bB + g * 4096 + ldsW);
    };

    auto compute = [&](int buf) {
        const char* bA = smem + buf * 12288;
        const char* bB = bA + 4096;
        f16x8 fa[2], fb[4];
        #pragma unroll
        for (int i = 0; i < 2; ++i) fa[i] = *(const f16x8*)(bA + offA[i]);
        #pragma unroll
        for (int i = 0; i < 4; ++i) fb[i] = *(const f16x8*)(bB + offB[i]);
        __builtin_amdgcn_s_setprio(1);
        #pragma unroll
        for (int mi = 0; mi < 2; ++mi)
            #pragma unroll
            for (int ni = 0; ni < 4; ++ni)
                acc[mi][ni] = __builtin_amdgcn_mfma_f32_16x16x32_f16(
                    fa[mi], fb[ni], acc[mi][ni], 0, 0, 0);
        __builtin_amdgcn_s_setprio(0);
    };

    stage(0, 0);
    __syncthreads();
    int buf = 0;
    #pragma unroll
    for (int kk = 0; kk < 16; ++kk) {
        if (kk < 15) stage(buf ^ 1, kk + 1);   // prefetch before compute
        compute(buf);
        __syncthreads();
        buf ^= 1;
    }

    // ---- epilogue: bias + activation -> LDS [64r][256B] transpose -> stores
    float bb[4];
    #pragma unroll
    for (int ni = 0; ni < 4; ++ni)
        bb[ni] = bias[n0 + wc * 64 + ni * 16 + l15];

    unsigned short* Hd = (unsigned short*)smem;   // 16KB 64x128 fp16 tile
    #pragma unroll
    for (int ni = 0; ni < 4; ++ni) {
        const int cl = wc * 64 + ni * 16 + l15;
        #pragma unroll
        for (int mi = 0; mi < 2; ++mi)
            #pragma unroll
            for (int r = 0; r < 4; ++r) {
                const int trl = wr * 32 + mi * 16 + lg * 4 + r;
                float g = acc[mi][ni][r] + bb[ni];
                float a = (gsel == 0) ? tanh_fast(g)
                        : (gsel == 1) ? sigmoidf_(-g)   // g = 1 - f
                                      : sigmoidf_(g);
                int byt = (trl << 8) + ((cl << 1) ^ (((trl >> 2) & 3) << 4));
                *(unsigned short*)((char*)Hd + byt) = f16b(a);
            }
    }
    __syncthreads();
    _Float16* Gg = (gsel == 0) ? Z : (gsel == 1) ? G : SO;
    const size_t gbase = (((size_t)(b * 4096 + t0)) << 8) + u0;  // halves
    #pragma unroll
    for (int i = 0; i < 4; ++i) {
        int off = (i * 256 + tid) << 4;        // bytes
        int row = off >> 8;                    // 256B LDS rows
        int cby = off & 255;
        int src = (row << 8) + (cby ^ (((row >> 2) & 3) << 4));
        int4 v = *(const int4*)((const char*)Hd + src);
        *(int4*)&Gg[gbase + ((size_t)row << 8) + (cby >> 1)] = v;
    }
}

// ---------- scan kernels
__global__ __launch_bounds__(256) void chunk_reduce(
    const _Float16* __restrict__ Z, const _Float16* __restrict__ G,
    float* __restrict__ CA, float* __restrict__ CB)
{
    const int u = threadIdx.x;
    const int blk = blockIdx.x;
    const int b = blk >> 6, ck = blk & 63;
    size_t base = (((size_t)b << 12) + ck * Lq) * 256 + u;
    float A = 1.f, Bv = 0.f;
    #pragma unroll 8
    for (int s = 0; s < Lq; ++s) {
        size_t idx = base + (size_t)s * 256;
        float g = (float)G[idx];
        float z = (float)Z[idx];
        Bv = fmaf(1.f - g, Bv, g * z);
        A *= (1.f - g);
    }
    size_t cidx = ((size_t)b * NCq + ck) * 256 + u;
    CA[cidx] = A;
    CB[cidx] = Bv;
}

// fused carry fold + apply (CA/CB written by previous launch = synced)
__global__ __launch_bounds__(256) void apply_scan(
    const _Float16* __restrict__ Z, const _Float16* __restrict__ G,
    const _Float16* __restrict__ SO, const float* __restrict__ CA,
    const float* __restrict__ CB, float* __restrict__ out)
{
    const int u = threadIdx.x;
    const int blk = blockIdx.x;
    const int b = blk >> 6, ck = blk & 63;
    float c = 0.f;
    for (int k = 0; k < ck; ++k) {
        size_t idx = ((size_t)b * NCq + k) * 256 + u;
        c = fmaf(CA[idx], c, CB[idx]);
    }
    size_t base = (((size_t)b << 12) + ck * Lq) * 256 + u;
    #pragma unroll 8
    for (int s = 0; s < Lq; ++s) {
        size_t idx = base + (size_t)s * 256;
        float g = (float)G[idx], z = (float)Z[idx];
        c = fmaf(1.f - g, c, g * z);
        out[idx] = (float)SO[idx] * c;
    }
}

extern "C" void kernel_launch(void* const* d_in, const int* in_sizes, int n_in,
                              void* d_out, int out_size, void* d_ws, size_t ws_size,
                              hipStream_t stream) {
    const float* x    = (const float*)d_in[0];
    const float* kw   = (const float*)d_in[1];
    const float* bias = (const float*)d_in[2];
    float* out = (float*)d_out;

    char* p = (char*)d_ws;
    _Float16* xh  = (_Float16*)p; p += (size_t)Bq * 4097 * 256 * 2;
    _Float16* bth = (_Float16*)p; p += (size_t)768 * 512 * 2;
    _Float16* Z   = (_Float16*)p; p += (size_t)Bq * Tq * 256 * 2;
    _Float16* G   = (_Float16*)p; p += (size_t)Bq * Tq * 256 * 2;
    _Float16* SO  = (_Float16*)p; p += (size_t)Bq * Tq * 256 * 2;
    float* CA  = (float*)p; p += (size_t)Bq * NCq * 256 * 4;
    float* CB  = (float*)p;

    const int NX = Bq * 4097 * 64;
    split_xk<<<(NX + 768 * 512 + 255) / 256, 256, 0, stream>>>(x, kw, xh, bth);
    dim3 g1(512, 6);
    conv_gemm<<<g1, 256, 0, stream>>>(xh, bth, bias, Z, G, SO);
    chunk_reduce<<<512, 256, 0, stream>>>(Z, G, CA, CB);
    apply_scan<<<512, 256, 0, stream>>>(Z, G, SO, CA, CB, out);
}

// Round 13
// 89.092 us; speedup vs baseline: 1.1314x; 1.0429x over previous
//
#include <hip/hip_runtime.h>
#include <math.h>

// QRNN: B=8, T=4096, C=256, UNITS=256, WINDOW=2
// gates = concat(x[t-1],x[t]) @ K[512,768] + bias ; z=tanh f=sig o=sig
// c_t = f*c_{t-1} + (1-f)*z_t ; h = sig(o)*c
// R13 = R4 structure (128x128 tile, BK=32, 2-buf LDS, plain syncthreads loop,
// best measured 49.9us) with 32x32x16 MFMA: 8 MFMA + 8 ds_read per wave-step
// (was 16+8) -> half the MFMA issue slots. C layout col=lane&31,
// row=(reg&3)+8*(reg>>2)+4*(lane>>5). Scan = R6 proven config.

#define Bq 8
#define Tq 4096
#define NCq 64
#define Lq 64

typedef __attribute__((ext_vector_type(8))) _Float16 f16x8;
typedef __attribute__((ext_vector_type(16))) float f32x16;

__device__ __forceinline__ float sigmoidf_(float x) {
    return 1.f / (1.f + __expf(-x));
}
__device__ __forceinline__ float tanh_fast(float x) {
    return 1.f - 2.f / (__expf(2.f * x) + 1.f);
}
__device__ __forceinline__ unsigned short f16b(float a) {
    _Float16 h = (_Float16)a;
    return *(unsigned short*)&h;
}
__device__ __forceinline__ void gload16(const void* g, void* l) {
    __builtin_amdgcn_global_load_lds(
        (const __attribute__((address_space(1))) void*)g,
        (__attribute__((address_space(3))) void*)l, 16, 0, 0);
}

// ---------- prep: x -> padded fp16 xp[b][t+1][c]  AND  kw -> transposed bth
__global__ __launch_bounds__(256) void split_xk(
    const float* __restrict__ x, const float* __restrict__ kw,
    _Float16* __restrict__ xh, _Float16* __restrict__ bh)
{
    const int NX = Bq * 4097 * 64;
    int idx = blockIdx.x * 256 + threadIdx.x;
    if (idx < NX) {
        int b  = idx / (4097 * 64);
        int r  = idx % (4097 * 64);
        int tp = r / 64, c4 = (r % 64) << 2;
        size_t o = ((size_t)(b * 4097 + tp) << 8) + c4;
        _Float16 h4[4] = {(_Float16)0.f, (_Float16)0.f, (_Float16)0.f, (_Float16)0.f};
        if (tp > 0) {
            const float4 v = *(const float4*)&x[((size_t)(b * 4096 + tp - 1) << 8) + c4];
            h4[0] = (_Float16)v.x; h4[1] = (_Float16)v.y;
            h4[2] = (_Float16)v.z; h4[3] = (_Float16)v.w;
        }
        *(ushort4*)&xh[o] = *(ushort4*)h4;
    } else {
        int j = idx - NX;
        if (j < 768 * 512) {
            int n = j >> 9, k = j & 511;
            bh[((size_t)n << 9) + k] = (_Float16)kw[(size_t)k * 768 + n];
        }
    }
}

// ---------- main GEMM: 128x128 tile, BK=32, 4 waves (2x2), 32x32x16 f16 MFMA
__global__ __launch_bounds__(256) void conv_gemm(
    const _Float16* __restrict__ xh, const _Float16* __restrict__ bth,
    const float* __restrict__ bias,
    _Float16* __restrict__ Z, _Float16* __restrict__ G, _Float16* __restrict__ SO)
{
    __shared__ __align__(16) char smem[32768];   // 2 bufs x (A 8KB + B 8KB)
    const int tid = threadIdx.x;
    const int l = tid & 63, w = tid >> 6;
    const int wr = w >> 1, wc = w & 1;           // wave tile 64x64
    const int l31 = l & 31, lh = l >> 5;         // lane row/col + k-half
    const int bm = blockIdx.x;            // 0..255  (M tiles)
    const int by = blockIdx.y;            // 0..5    (N tiles)
    const int b  = bm >> 5;
    const int t0 = (bm & 31) << 7;
    const int n0 = by << 7;

    f32x16 acc[2][2] = {};

    // staging (verbatim R4): LDS linear dest; source k pre-swizzled so
    // LDS(row, slot) holds k-group (slot ^ ((row>>1)&3))
    const int rowT   = tid >> 2;
    const int slotSw = (tid & 3) ^ ((rowT >> 1) & 3);
    size_t gaBase = ((size_t)(b * 4097 + t0 + rowT) << 8) + (slotSw << 3);
    size_t gbBase = ((size_t)(n0 + rowT) << 9) + (slotSw << 3);
    const int ldsW = w << 9;   // halves: wave base (w*1024 bytes)

    // frag offsets: tile row ra, k-group kg=(kh*2+lh) -> slot kg^((ra>>1)&3)
    int offA[2][2], offB[2][2];
    #pragma unroll
    for (int i = 0; i < 2; ++i) {
        int ra = wr * 64 + i * 32 + l31;
        int rb = wc * 64 + i * 32 + l31;
        #pragma unroll
        for (int kh = 0; kh < 2; ++kh) {
            offA[i][kh] = (ra << 6) + ((((kh << 1) + lh) ^ ((ra >> 1) & 3)) << 4);
            offB[i][kh] = (rb << 6) + ((((kh << 1) + lh) ^ ((rb >> 1) & 3)) << 4);
        }
    }

    auto stage = [&](int buf, int kk) {
        _Float16* pA = (_Float16*)smem + buf * 8192 + ldsW;
        _Float16* pB = pA + 4096;
        size_t ga = gaBase + (size_t)kk * 32;   // rolls into next t-row for kk>=8
        size_t gb = gbBase + (size_t)kk * 32;
        gload16(xh  + ga,          pA);
        gload16(xh  + ga + 16384,  pA + 2048);   // rows +64 (A row = 256 halves)
        gload16(bth + gb,          pB);
        gload16(bth + gb + 32768,  pB + 2048);   // rows +64 (B row = 512 halves)
    };

    auto compute = [&](int buf) {
        const char* bA = (const char*)smem + buf * 16384;
        const char* bB = bA + 8192;
        f16x8 fa[2][2], fb[2][2];
        #pragma unroll
        for (int i = 0; i < 2; ++i)
            #pragma unroll
            for (int kh = 0; kh < 2; ++kh) {
                fa[i][kh] = *(const f16x8*)(bA + offA[i][kh]);
                fb[i][kh] = *(const f16x8*)(bB + offB[i][kh]);
            }
        #pragma unroll
        for (int mi = 0; mi < 2; ++mi)
            #pragma unroll
            for (int ni = 0; ni < 2; ++ni)
                #pragma unroll
                for (int kh = 0; kh < 2; ++kh)
                    acc[mi][ni] = __builtin_amdgcn_mfma_f32_32x32x16_f16(
                        fa[mi][kh], fb[ni][kh], acc[mi][ni], 0, 0, 0);
    };

    stage(0, 0);
    __syncthreads();
    int buf = 0;
    #pragma unroll
    for (int kk = 0; kk < 16; ++kk) {
        if (kk < 15) stage(buf ^ 1, kk + 1);   // prefetch before compute
        compute(buf);
        __syncthreads();
        buf ^= 1;
    }

    // ---- epilogue: bias + activation, LDS transpose, coalesced fp16 stores ----
    const int gsel = by >> 1;   // 0:z 1:f(store g=1-f) 2:o
    float bb[2];
    #pragma unroll
    for (int ni = 0; ni < 2; ++ni)
        bb[ni] = bias[n0 + wc * 64 + ni * 32 + l31];

    unsigned short* Hd = (unsigned short*)smem;   // 32KB 128x128 fp16 tile
    #pragma unroll
    for (int ni = 0; ni < 2; ++ni) {
        const int cl = wc * 64 + ni * 32 + l31;
        #pragma unroll
        for (int mi = 0; mi < 2; ++mi)
            #pragma unroll
            for (int q = 0; q < 16; ++q) {
                // C layout: row = (q&3) + 8*(q>>2) + 4*lh
                const int trl = wr * 64 + mi * 32 + (q & 3) + ((q >> 2) << 3) + (lh << 2);
                float g = acc[mi][ni][q] + bb[ni];
                float a = (gsel == 0) ? tanh_fast(g)
                        : (gsel == 1) ? sigmoidf_(-g)   // g = 1 - f
                                      : sigmoidf_(g);
                int byt = (trl << 8) + ((cl << 1) ^ (((trl >> 2) & 3) << 4));
                *(unsigned short*)((char*)Hd + byt) = f16b(a);
            }
    }
    __syncthreads();
    _Float16* Gg = (gsel == 0) ? Z : (gsel == 1) ? G : SO;
    const int u0 = n0 & 255;
    const size_t gbase = ((size_t)(b * 4096 + t0) << 8) + u0;  // halves
    #pragma unroll
    for (int j = 0; j < 8; ++j) {
        int hoff = tid * 8 + j * 2048;         // halves
        int row  = hoff >> 7;
        int cby  = (hoff & 127) << 1;          // bytes within row
        int srcB = (row << 8) + (cby ^ (((row >> 2) & 3) << 4));
        int4 v = *(const int4*)((const char*)Hd + srcB);
        *(int4*)&Gg[gbase + ((size_t)row << 8) + (cby >> 1)] = v;
    }
}

// ---------- scan kernels (R6 proven config)
__global__ __launch_bounds__(256) void chunk_reduce(
    const _Float16* __restrict__ Z, const _Float16* __restrict__ G,
    float* __restrict__ CA, float* __restrict__ CB)
{
    const int u = threadIdx.x;
    const int blk = blockIdx.x;
    const int b = blk >> 6, ck = blk & 63;
    size_t base = (((size_t)b << 12) + ck * Lq) * 256 + u;
    float A = 1.f, Bv = 0.f;
    #pragma unroll 8
    for (int s = 0; s < Lq; ++s) {
        size_t idx = base + (size_t)s * 256;
        float g = (float)G[idx];
        float z = (float)Z[idx];
        Bv = fmaf(1.f - g, Bv, g * z);
        A *= (1.f - g);
    }
    size_t cidx = ((size_t)b * NCq + ck) * 256 + u;
    CA[cidx] = A;
    CB[cidx] = Bv;
}

__global__ __launch_bounds__(256) void carry_scan(
    const float* __restrict__ CA, const float* __restrict__ CB,
    float* __restrict__ CIN)
{
    const int u = threadIdx.x;
    const int b = blockIdx.x;
    float c = 0.f;
    #pragma unroll 8
    for (int k = 0; k < NCq; ++k) {
        size_t idx = ((size_t)b * NCq + k) * 256 + u;
        CIN[idx] = c;
        c = fmaf(CA[idx], c, CB[idx]);
    }
}

__global__ __launch_bounds__(256) void apply_scan(
    const _Float16* __restrict__ Z, const _Float16* __restrict__ G,
    const _Float16* __restrict__ SO, const float* __restrict__ CIN,
    float* __restrict__ out)
{
    const int u = threadIdx.x;
    const int blk = blockIdx.x;
    const int b = blk >> 6, ck = blk & 63;
    float c = CIN[((size_t)b * NCq + ck) * 256 + u];
    size_t base = (((size_t)b << 12) + ck * Lq) * 256 + u;
    #pragma unroll 8
    for (int s = 0; s < Lq; ++s) {
        size_t idx = base + (size_t)s * 256;
        float g = (float)G[idx], z = (float)Z[idx];
        c = fmaf(1.f - g, c, g * z);
        out[idx] = (float)SO[idx] * c;
    }
}

extern "C" void kernel_launch(void* const* d_in, const int* in_sizes, int n_in,
                              void* d_out, int out_size, void* d_ws, size_t ws_size,
                              hipStream_t stream) {
    const float* x    = (const float*)d_in[0];
    const float* kw   = (const float*)d_in[1];
    const float* bias = (const float*)d_in[2];
    float* out = (float*)d_out;

    char* p = (char*)d_ws;
    _Float16* xh  = (_Float16*)p; p += (size_t)Bq * 4097 * 256 * 2;
    _Float16* bth = (_Float16*)p; p += (size_t)768 * 512 * 2;
    _Float16* Z   = (_Float16*)p; p += (size_t)Bq * Tq * 256 * 2;
    _Float16* G   = (_Float16*)p; p += (size_t)Bq * Tq * 256 * 2;
    _Float16* SO  = (_Float16*)p; p += (size_t)Bq * Tq * 256 * 2;
    float* CA  = (float*)p; p += (size_t)Bq * NCq * 256 * 4;
    float* CB  = (float*)p; p += (size_t)Bq * NCq * 256 * 4;
    float* CIN = (float*)p;

    const int NX = Bq * 4097 * 64;
    split_xk<<<(NX + 768 * 512 + 255) / 256, 256, 0, stream>>>(x, kw, xh, bth);
    dim3 g1(256, 6);
    conv_gemm<<<g1, 256, 0, stream>>>(xh, bth, bias, Z, G, SO);
    chunk_reduce<<<512, 256, 0, stream>>>(Z, G, CA, CB);
    carry_scan<<<Bq, 256, 0, stream>>>(CA, CB, CIN);
    apply_scan<<<512, 256, 0, stream>>>(Z, G, SO, CIN, out);
}